// Round 3
// baseline (93.208 us; speedup 1.0000x reference)
//
#include <hip/hip_runtime.h>

// LIF scan: per neuron i, over t: m = beta*m + x[t,i]; s = (m>=thr);
// spikes[t,i]=s; membranes[t,i]=m; m -= thr*s.
// x: (T, B*N) f32. d_out = [spikes (T*B*N) | membranes (T*B*N)] f32.
//
// R1: float4/thread, 1024 blocks, 95.3us (4.2 TB/s eff).
// R2: +nt loads/stores, 87.9us (4.6 TB/s eff) — not BW-bound; only 4
//     waves/SIMD and a 32-deep serial t-chain per thread => latency-bound.
// R3: float2/thread => 8192 waves (8/SIMD), 2x TLP. Target ~64us
//     (402MB mandatory @ ~6.3 TB/s).

typedef float f32x2 __attribute__((ext_vector_type(2)));

#define LIF_BETA 0.25f
#define LIF_THR  1.0f
#define LIF_T    32

__global__ __launch_bounds__(256) void lif_scan_kernel(
    const f32x2* __restrict__ x,
    f32x2* __restrict__ spikes,
    f32x2* __restrict__ membranes,
    int bn2)  // (B*N)/2
{
    int i = blockIdx.x * blockDim.x + threadIdx.x;
    if (i >= bn2) return;

    f32x2 m = {0.f, 0.f};

#pragma unroll
    for (int t = 0; t < LIF_T; ++t) {
        size_t idx = (size_t)t * (size_t)bn2 + (size_t)i;
        f32x2 xv = __builtin_nontemporal_load(&x[idx]);

        m.x = LIF_BETA * m.x + xv.x;
        m.y = LIF_BETA * m.y + xv.y;

        f32x2 s;
        s.x = (m.x >= LIF_THR) ? 1.0f : 0.0f;
        s.y = (m.y >= LIF_THR) ? 1.0f : 0.0f;

        __builtin_nontemporal_store(s, &spikes[idx]);
        __builtin_nontemporal_store(m, &membranes[idx]);  // pre-reset membrane

        m.x -= LIF_THR * s.x;
        m.y -= LIF_THR * s.y;
    }
}

extern "C" void kernel_launch(void* const* d_in, const int* in_sizes, int n_in,
                              void* d_out, int out_size, void* d_ws, size_t ws_size,
                              hipStream_t stream) {
    (void)n_in; (void)d_ws; (void)ws_size;

    const float* x = (const float*)d_in[0];
    float* out = (float*)d_out;

    const int total = in_sizes[0];          // T * B * N
    const int bn = total / LIF_T;           // B * N = 1,048,576
    const int bn2 = bn / 2;                 // 524,288

    float* spikes = out;                    // first T*B*N floats
    float* membranes = out + (size_t)total; // second T*B*N floats

    const int block = 256;
    const int grid = (bn2 + block - 1) / block;  // 2048 blocks

    lif_scan_kernel<<<grid, block, 0, stream>>>(
        (const f32x2*)x, (f32x2*)spikes, (f32x2*)membranes, bn2);
}

// Round 4
// 74.793 us; speedup vs baseline: 1.2462x; 1.2462x over previous
//
#include <hip/hip_runtime.h>

// LIF scan: per neuron i, over t: m = beta*m + x[t,i]; s = (m>=thr);
// spikes[t,i]=s; membranes[t,i]=m; m -= thr*s.
// x: (T, B*N) f32. d_out = [spikes (T*B*N) | membranes (T*B*N)] f32.
//
// R1: float4, plain ld/st:            95.3us (4.2 TB/s eff)
// R2: float4, nt ld + nt st:          87.9us (4.6 TB/s eff)
// R3: float2, nt ld + nt st, 2x TLP:  93.2us  (worse -> not TLP-bound)
// Fill-kernel counters: 1GiB store w/ FETCH~22MB => stores don't RFO.
// R4 theory: x (128MiB) fits the 256MiB Infinity Cache and is re-read every
// replay. nt loads (R2/R3) forbid caching it; plain stores (R1) evict it.
// Use CACHING loads (x stays L3-resident) + NT stores (outputs don't
// pollute). Write-bound floor ~268MB/7TB/s ~= 38us + L3 reads => ~55-68us.

typedef float f32x4 __attribute__((ext_vector_type(4)));

#define LIF_BETA 0.25f
#define LIF_THR  1.0f
#define LIF_T    32

__global__ __launch_bounds__(256) void lif_scan_kernel(
    const f32x4* __restrict__ x,
    f32x4* __restrict__ spikes,
    f32x4* __restrict__ membranes,
    int bn4)  // (B*N)/4
{
    int i = blockIdx.x * blockDim.x + threadIdx.x;
    if (i >= bn4) return;

    f32x4 m = {0.f, 0.f, 0.f, 0.f};

#pragma unroll
    for (int t = 0; t < LIF_T; ++t) {
        size_t idx = (size_t)t * (size_t)bn4 + (size_t)i;
        f32x4 xv = x[idx];  // caching load: keep x resident in L2/L3

        m.x = LIF_BETA * m.x + xv.x;
        m.y = LIF_BETA * m.y + xv.y;
        m.z = LIF_BETA * m.z + xv.z;
        m.w = LIF_BETA * m.w + xv.w;

        f32x4 s;
        s.x = (m.x >= LIF_THR) ? 1.0f : 0.0f;
        s.y = (m.y >= LIF_THR) ? 1.0f : 0.0f;
        s.z = (m.z >= LIF_THR) ? 1.0f : 0.0f;
        s.w = (m.w >= LIF_THR) ? 1.0f : 0.0f;

        // NT stores: write-once streams, don't evict x from L2/L3
        __builtin_nontemporal_store(s, &spikes[idx]);
        __builtin_nontemporal_store(m, &membranes[idx]);  // pre-reset membrane

        m.x -= LIF_THR * s.x;
        m.y -= LIF_THR * s.y;
        m.z -= LIF_THR * s.z;
        m.w -= LIF_THR * s.w;
    }
}

extern "C" void kernel_launch(void* const* d_in, const int* in_sizes, int n_in,
                              void* d_out, int out_size, void* d_ws, size_t ws_size,
                              hipStream_t stream) {
    (void)n_in; (void)d_ws; (void)ws_size;

    const float* x = (const float*)d_in[0];
    float* out = (float*)d_out;

    const int total = in_sizes[0];          // T * B * N
    const int bn = total / LIF_T;           // B * N = 1,048,576
    const int bn4 = bn / 4;                 // 262,144

    float* spikes = out;                    // first T*B*N floats
    float* membranes = out + (size_t)total; // second T*B*N floats

    const int block = 256;
    const int grid = (bn4 + block - 1) / block;  // 1024 blocks

    lif_scan_kernel<<<grid, block, 0, stream>>>(
        (const f32x4*)x, (f32x4*)spikes, (f32x4*)membranes, bn4);
}

// Round 5
// 74.776 us; speedup vs baseline: 1.2465x; 1.0002x over previous
//
#include <hip/hip_runtime.h>

// LIF scan: per neuron i, over t: m = beta*m + x[t,i]; s = (m>=thr);
// spikes[t,i]=s; membranes[t,i]=m; m -= thr*s.
// x: (T, B*N) f32. d_out = [spikes (T*B*N) | membranes (T*B*N)] f32.
//
// R1: float4, plain ld/st:            95.3us (4.2 TB/s eff)
// R2: float4, nt ld + nt st:          87.9us
// R3: float2, nt ld + nt st:          93.2us (more TLP hurt)
// R4: float4, caching ld + nt st:     74.8us (5.37 TB/s eff) — best combo;
//     x stays cache-resident, stores don't pollute.
// R5: add explicit depth-3 rotating prefetch so each wave keeps ~3
//     independent 1KB loads in flight while storing (compiler's own
//     schedule waits vmcnt down on the just-issued load). Target 60-66us
//     (402MB mandatory @ ~6.7 TB/s mixed-stream ceiling).

typedef float f32x4 __attribute__((ext_vector_type(4)));

#define LIF_BETA 0.25f
#define LIF_THR  1.0f
#define LIF_T    32

__global__ __launch_bounds__(256) void lif_scan_kernel(
    const f32x4* __restrict__ x,
    f32x4* __restrict__ spikes,
    f32x4* __restrict__ membranes,
    int bn4)  // (B*N)/4
{
    int i = blockIdx.x * blockDim.x + threadIdx.x;
    if (i >= bn4) return;

    f32x4 m = {0.f, 0.f, 0.f, 0.f};

    // depth-3 rotating prefetch buffers (caching loads: keep x L2/L3-resident)
    f32x4 buf0 = x[(size_t)0 * bn4 + i];
    f32x4 buf1 = x[(size_t)1 * bn4 + i];
    f32x4 buf2 = x[(size_t)2 * bn4 + i];

#pragma unroll
    for (int t = 0; t < LIF_T; ++t) {
        f32x4 xv = buf0;
        buf0 = buf1;
        buf1 = buf2;
        if (t + 3 < LIF_T)
            buf2 = x[(size_t)(t + 3) * bn4 + i];  // prefetch 3 ahead

        m.x = LIF_BETA * m.x + xv.x;
        m.y = LIF_BETA * m.y + xv.y;
        m.z = LIF_BETA * m.z + xv.z;
        m.w = LIF_BETA * m.w + xv.w;

        f32x4 s;
        s.x = (m.x >= LIF_THR) ? 1.0f : 0.0f;
        s.y = (m.y >= LIF_THR) ? 1.0f : 0.0f;
        s.z = (m.z >= LIF_THR) ? 1.0f : 0.0f;
        s.w = (m.w >= LIF_THR) ? 1.0f : 0.0f;

        size_t idx = (size_t)t * (size_t)bn4 + (size_t)i;
        // NT stores: write-once streams, bypass/stream past L2-L3
        __builtin_nontemporal_store(s, &spikes[idx]);
        __builtin_nontemporal_store(m, &membranes[idx]);  // pre-reset membrane

        m.x -= LIF_THR * s.x;
        m.y -= LIF_THR * s.y;
        m.z -= LIF_THR * s.z;
        m.w -= LIF_THR * s.w;
    }
}

extern "C" void kernel_launch(void* const* d_in, const int* in_sizes, int n_in,
                              void* d_out, int out_size, void* d_ws, size_t ws_size,
                              hipStream_t stream) {
    (void)n_in; (void)d_ws; (void)ws_size;

    const float* x = (const float*)d_in[0];
    float* out = (float*)d_out;

    const int total = in_sizes[0];          // T * B * N
    const int bn = total / LIF_T;           // B * N = 1,048,576
    const int bn4 = bn / 4;                 // 262,144

    float* spikes = out;                    // first T*B*N floats
    float* membranes = out + (size_t)total; // second T*B*N floats

    const int block = 256;
    const int grid = (bn4 + block - 1) / block;  // 1024 blocks

    lif_scan_kernel<<<grid, block, 0, stream>>>(
        (const f32x4*)x, (f32x4*)spikes, (f32x4*)membranes, bn4);
}

// Round 6
// 67.323 us; speedup vs baseline: 1.3845x; 1.1107x over previous
//
#include <hip/hip_runtime.h>

// LIF scan: per neuron i, over t: m = beta*m + x[t,i]; s = (m>=thr);
// spikes[t,i]=s; membranes[t,i]=m; m -= thr*s.
// x: (T, B*N) f32. d_out = [spikes | membranes] f32.
//
// R1: float4, plain ld/st:            95.3us
// R2: float4, nt ld + nt st:          87.9us
// R3: float2, nt ld + nt st:          93.2us (more TLP hurt)
// R4: float4, caching ld + nt st:     74.8us (best; 5.37 TB/s eff)
// R5: +depth-3 rotating prefetch:     74.8us (unchanged -> MLP not the wall)
// R6: ILP-2 burst-widening: 512 wgs, each thread owns columns (i, i+256);
//     wg covers 8KB contiguous per stream per t (vs 4KB), halving the
//     number of interleaved DRAM streams. 2 independent chains/thread.
//     Target ~65-70us if row-buffer locality is the wall; unchanged =>
//     declare ~75us the practical ceiling for this 3-stream pattern.

typedef float f32x4 __attribute__((ext_vector_type(4)));

#define LIF_BETA 0.25f
#define LIF_THR  1.0f
#define LIF_T    32

__global__ __launch_bounds__(256) void lif_scan_kernel(
    const f32x4* __restrict__ x,
    f32x4* __restrict__ spikes,
    f32x4* __restrict__ membranes,
    int bn4)  // (B*N)/4
{
    // Each workgroup owns a 512-wide contiguous chunk of float4 columns.
    int base = blockIdx.x * 512 + threadIdx.x;
    int i0 = base;          // column A
    int i1 = base + 256;    // column B (adjacent chunk, coalesced)
    if (i1 >= bn4) return;  // (exact fit for bn4 = 262144, 512 blocks)

    f32x4 mA = {0.f, 0.f, 0.f, 0.f};
    f32x4 mB = {0.f, 0.f, 0.f, 0.f};

#pragma unroll
    for (int t = 0; t < LIF_T; ++t) {
        size_t rowoff = (size_t)t * (size_t)bn4;
        // two independent caching loads, back-to-back (2x MLP, 8KB/wg burst)
        f32x4 xA = x[rowoff + i0];
        f32x4 xB = x[rowoff + i1];

        mA.x = LIF_BETA * mA.x + xA.x;  mB.x = LIF_BETA * mB.x + xB.x;
        mA.y = LIF_BETA * mA.y + xA.y;  mB.y = LIF_BETA * mB.y + xB.y;
        mA.z = LIF_BETA * mA.z + xA.z;  mB.z = LIF_BETA * mB.z + xB.z;
        mA.w = LIF_BETA * mA.w + xA.w;  mB.w = LIF_BETA * mB.w + xB.w;

        f32x4 sA, sB;
        sA.x = (mA.x >= LIF_THR) ? 1.0f : 0.0f;
        sA.y = (mA.y >= LIF_THR) ? 1.0f : 0.0f;
        sA.z = (mA.z >= LIF_THR) ? 1.0f : 0.0f;
        sA.w = (mA.w >= LIF_THR) ? 1.0f : 0.0f;
        sB.x = (mB.x >= LIF_THR) ? 1.0f : 0.0f;
        sB.y = (mB.y >= LIF_THR) ? 1.0f : 0.0f;
        sB.z = (mB.z >= LIF_THR) ? 1.0f : 0.0f;
        sB.w = (mB.w >= LIF_THR) ? 1.0f : 0.0f;

        // NT stores: write-once streams, don't pollute L2
        __builtin_nontemporal_store(sA, &spikes[rowoff + i0]);
        __builtin_nontemporal_store(sB, &spikes[rowoff + i1]);
        __builtin_nontemporal_store(mA, &membranes[rowoff + i0]);  // pre-reset
        __builtin_nontemporal_store(mB, &membranes[rowoff + i1]);

        mA.x -= LIF_THR * sA.x;  mB.x -= LIF_THR * sB.x;
        mA.y -= LIF_THR * sA.y;  mB.y -= LIF_THR * sB.y;
        mA.z -= LIF_THR * sA.z;  mB.z -= LIF_THR * sB.z;
        mA.w -= LIF_THR * sA.w;  mB.w -= LIF_THR * sB.w;
    }
}

extern "C" void kernel_launch(void* const* d_in, const int* in_sizes, int n_in,
                              void* d_out, int out_size, void* d_ws, size_t ws_size,
                              hipStream_t stream) {
    (void)n_in; (void)d_ws; (void)ws_size;

    const float* x = (const float*)d_in[0];
    float* out = (float*)d_out;

    const int total = in_sizes[0];          // T * B * N
    const int bn = total / LIF_T;           // B * N = 1,048,576
    const int bn4 = bn / 4;                 // 262,144

    float* spikes = out;                    // first T*B*N floats
    float* membranes = out + (size_t)total; // second T*B*N floats

    const int block = 256;
    const int grid = bn4 / 512;             // 512 blocks, 2 float4/thread

    lif_scan_kernel<<<grid, block, 0, stream>>>(
        (const f32x4*)x, (f32x4*)spikes, (f32x4*)membranes, bn4);
}

// Round 7
// 63.169 us; speedup vs baseline: 1.4755x; 1.0658x over previous
//
#include <hip/hip_runtime.h>

// LIF scan: per neuron i, over t: m = beta*m + x[t,i]; s = (m>=thr);
// spikes[t,i]=s; membranes[t,i]=m; m -= thr*s.
// x: (T, B*N) f32. d_out = [spikes | membranes] f32.
//
// R1: float4, plain ld/st:            95.3us
// R2: float4, nt ld + nt st:          87.9us
// R3: float2, nt ld + nt st:          93.2us (more TLP hurt)
// R4: float4, caching ld + nt st:     74.8us
// R5: +depth-3 rotating prefetch:     74.8us (MLP not the wall)
// R6: ILP-2, 512 wgs, 8KB/stream/t:   67.3us (5.97 TB/s eff) — DRAM stream
//     locality is the lever.
// R7: ILP-4, 256 wgs, 16KB contiguous per stream per t, 768 total streams.
//     Target 61-65us; flat/worse => declare ~67us roofline (95% of copy
//     ceiling).

typedef float f32x4 __attribute__((ext_vector_type(4)));

#define LIF_BETA 0.25f
#define LIF_THR  1.0f
#define LIF_T    32

__global__ __launch_bounds__(256) void lif_scan_kernel(
    const f32x4* __restrict__ x,
    f32x4* __restrict__ spikes,
    f32x4* __restrict__ membranes,
    int bn4)  // (B*N)/4
{
    // Each workgroup owns a 1024-wide contiguous chunk of float4 columns.
    int base = blockIdx.x * 1024 + threadIdx.x;
    int i0 = base;
    int i1 = base + 256;
    int i2 = base + 512;
    int i3 = base + 768;
    if (i3 >= bn4) return;  // exact fit: bn4 = 262144, 256 blocks

    f32x4 m0 = {0.f, 0.f, 0.f, 0.f};
    f32x4 m1 = {0.f, 0.f, 0.f, 0.f};
    f32x4 m2 = {0.f, 0.f, 0.f, 0.f};
    f32x4 m3 = {0.f, 0.f, 0.f, 0.f};

#pragma unroll
    for (int t = 0; t < LIF_T; ++t) {
        size_t rowoff = (size_t)t * (size_t)bn4;
        // four independent caching loads (16KB/wg burst per stream)
        f32x4 x0 = x[rowoff + i0];
        f32x4 x1 = x[rowoff + i1];
        f32x4 x2 = x[rowoff + i2];
        f32x4 x3 = x[rowoff + i3];

        m0.x = LIF_BETA * m0.x + x0.x;  m0.y = LIF_BETA * m0.y + x0.y;
        m0.z = LIF_BETA * m0.z + x0.z;  m0.w = LIF_BETA * m0.w + x0.w;
        m1.x = LIF_BETA * m1.x + x1.x;  m1.y = LIF_BETA * m1.y + x1.y;
        m1.z = LIF_BETA * m1.z + x1.z;  m1.w = LIF_BETA * m1.w + x1.w;
        m2.x = LIF_BETA * m2.x + x2.x;  m2.y = LIF_BETA * m2.y + x2.y;
        m2.z = LIF_BETA * m2.z + x2.z;  m2.w = LIF_BETA * m2.w + x2.w;
        m3.x = LIF_BETA * m3.x + x3.x;  m3.y = LIF_BETA * m3.y + x3.y;
        m3.z = LIF_BETA * m3.z + x3.z;  m3.w = LIF_BETA * m3.w + x3.w;

        f32x4 s0, s1, s2, s3;
        s0.x = (m0.x >= LIF_THR) ? 1.0f : 0.0f;
        s0.y = (m0.y >= LIF_THR) ? 1.0f : 0.0f;
        s0.z = (m0.z >= LIF_THR) ? 1.0f : 0.0f;
        s0.w = (m0.w >= LIF_THR) ? 1.0f : 0.0f;
        s1.x = (m1.x >= LIF_THR) ? 1.0f : 0.0f;
        s1.y = (m1.y >= LIF_THR) ? 1.0f : 0.0f;
        s1.z = (m1.z >= LIF_THR) ? 1.0f : 0.0f;
        s1.w = (m1.w >= LIF_THR) ? 1.0f : 0.0f;
        s2.x = (m2.x >= LIF_THR) ? 1.0f : 0.0f;
        s2.y = (m2.y >= LIF_THR) ? 1.0f : 0.0f;
        s2.z = (m2.z >= LIF_THR) ? 1.0f : 0.0f;
        s2.w = (m2.w >= LIF_THR) ? 1.0f : 0.0f;
        s3.x = (m3.x >= LIF_THR) ? 1.0f : 0.0f;
        s3.y = (m3.y >= LIF_THR) ? 1.0f : 0.0f;
        s3.z = (m3.z >= LIF_THR) ? 1.0f : 0.0f;
        s3.w = (m3.w >= LIF_THR) ? 1.0f : 0.0f;

        // NT stores: write-once streams, don't pollute L2
        __builtin_nontemporal_store(s0, &spikes[rowoff + i0]);
        __builtin_nontemporal_store(s1, &spikes[rowoff + i1]);
        __builtin_nontemporal_store(s2, &spikes[rowoff + i2]);
        __builtin_nontemporal_store(s3, &spikes[rowoff + i3]);
        __builtin_nontemporal_store(m0, &membranes[rowoff + i0]);  // pre-reset
        __builtin_nontemporal_store(m1, &membranes[rowoff + i1]);
        __builtin_nontemporal_store(m2, &membranes[rowoff + i2]);
        __builtin_nontemporal_store(m3, &membranes[rowoff + i3]);

        m0.x -= LIF_THR * s0.x;  m0.y -= LIF_THR * s0.y;
        m0.z -= LIF_THR * s0.z;  m0.w -= LIF_THR * s0.w;
        m1.x -= LIF_THR * s1.x;  m1.y -= LIF_THR * s1.y;
        m1.z -= LIF_THR * s1.z;  m1.w -= LIF_THR * s1.w;
        m2.x -= LIF_THR * s2.x;  m2.y -= LIF_THR * s2.y;
        m2.z -= LIF_THR * s2.z;  m2.w -= LIF_THR * s2.w;
        m3.x -= LIF_THR * s3.x;  m3.y -= LIF_THR * s3.y;
        m3.z -= LIF_THR * s3.z;  m3.w -= LIF_THR * s3.w;
    }
}

extern "C" void kernel_launch(void* const* d_in, const int* in_sizes, int n_in,
                              void* d_out, int out_size, void* d_ws, size_t ws_size,
                              hipStream_t stream) {
    (void)n_in; (void)d_ws; (void)ws_size;

    const float* x = (const float*)d_in[0];
    float* out = (float*)d_out;

    const int total = in_sizes[0];          // T * B * N
    const int bn = total / LIF_T;           // B * N = 1,048,576
    const int bn4 = bn / 4;                 // 262,144

    float* spikes = out;                    // first T*B*N floats
    float* membranes = out + (size_t)total; // second T*B*N floats

    const int block = 256;
    const int grid = bn4 / 1024;            // 256 blocks, 4 float4/thread

    lif_scan_kernel<<<grid, block, 0, stream>>>(
        (const f32x4*)x, (f32x4*)spikes, (f32x4*)membranes, bn4);
}

// Round 8
// 60.841 us; speedup vs baseline: 1.5320x; 1.0383x over previous
//
#include <hip/hip_runtime.h>

// LIF scan: per neuron i, over t: m = beta*m + x[t,i]; s = (m>=thr);
// spikes[t,i]=s; membranes[t,i]=m; m -= thr*s.
// x: (T, B*N) f32. d_out = [spikes | membranes] f32.
//
// R1: float4, plain ld/st:            95.3us
// R2: float4, nt ld + nt st:          87.9us
// R3: float2, nt ld + nt st:          93.2us (more TLP hurt)
// R4: float4, caching ld + nt st:     74.8us
// R5: +depth-3 rotating prefetch:     74.8us (MLP not the wall)
// R6: ILP-2, 512 wgs, 8KB/stream/t:   67.3us (5.97 TB/s)
// R7: ILP-4, 256 wgs, 16KB/stream/t:  63.2us (6.36 TB/s) — stream locality
//     keeps paying; 1 wave/SIMD suffices, so CU count is not the limit.
// R8: ILP-8, 128 wgs, 32KB contiguous per stream per t, ~384 streams.
//     Target 58-61us; flat/worse => R7 is the roofline (~6.4 TB/s eff).

typedef float f32x4 __attribute__((ext_vector_type(4)));

#define LIF_BETA 0.25f
#define LIF_THR  1.0f
#define LIF_T    32

__global__ __launch_bounds__(256) void lif_scan_kernel(
    const f32x4* __restrict__ x,
    f32x4* __restrict__ spikes,
    f32x4* __restrict__ membranes,
    int bn4)  // (B*N)/4
{
    // Each workgroup owns a 2048-wide contiguous chunk of float4 columns.
    int base = blockIdx.x * 2048 + threadIdx.x;
    if (base + 1792 >= bn4) {
        if (base >= bn4) return;  // safety; exact fit for bn4=262144, 128 wgs
    }

    f32x4 m[8];
#pragma unroll
    for (int c = 0; c < 8; ++c) m[c] = (f32x4){0.f, 0.f, 0.f, 0.f};

#pragma unroll
    for (int t = 0; t < LIF_T; ++t) {
        size_t rowoff = (size_t)t * (size_t)bn4;

        f32x4 xv[8];
#pragma unroll
        for (int c = 0; c < 8; ++c)
            xv[c] = x[rowoff + base + (size_t)(c * 256)];  // caching loads

        f32x4 s[8];
#pragma unroll
        for (int c = 0; c < 8; ++c) {
            m[c].x = LIF_BETA * m[c].x + xv[c].x;
            m[c].y = LIF_BETA * m[c].y + xv[c].y;
            m[c].z = LIF_BETA * m[c].z + xv[c].z;
            m[c].w = LIF_BETA * m[c].w + xv[c].w;
            s[c].x = (m[c].x >= LIF_THR) ? 1.0f : 0.0f;
            s[c].y = (m[c].y >= LIF_THR) ? 1.0f : 0.0f;
            s[c].z = (m[c].z >= LIF_THR) ? 1.0f : 0.0f;
            s[c].w = (m[c].w >= LIF_THR) ? 1.0f : 0.0f;
        }

        // NT stores, grouped by output array for max per-array burst width
#pragma unroll
        for (int c = 0; c < 8; ++c)
            __builtin_nontemporal_store(s[c], &spikes[rowoff + base + (size_t)(c * 256)]);
#pragma unroll
        for (int c = 0; c < 8; ++c)
            __builtin_nontemporal_store(m[c], &membranes[rowoff + base + (size_t)(c * 256)]);

#pragma unroll
        for (int c = 0; c < 8; ++c) {
            m[c].x -= LIF_THR * s[c].x;
            m[c].y -= LIF_THR * s[c].y;
            m[c].z -= LIF_THR * s[c].z;
            m[c].w -= LIF_THR * s[c].w;
        }
    }
}

extern "C" void kernel_launch(void* const* d_in, const int* in_sizes, int n_in,
                              void* d_out, int out_size, void* d_ws, size_t ws_size,
                              hipStream_t stream) {
    (void)n_in; (void)d_ws; (void)ws_size;

    const float* x = (const float*)d_in[0];
    float* out = (float*)d_out;

    const int total = in_sizes[0];          // T * B * N
    const int bn = total / LIF_T;           // B * N = 1,048,576
    const int bn4 = bn / 4;                 // 262,144

    float* spikes = out;                    // first T*B*N floats
    float* membranes = out + (size_t)total; // second T*B*N floats

    const int block = 256;
    const int grid = bn4 / 2048;            // 128 blocks, 8 float4/thread

    lif_scan_kernel<<<grid, block, 0, stream>>>(
        (const f32x4*)x, (f32x4*)spikes, (f32x4*)membranes, bn4);
}